// Round 10
// baseline (2144.385 us; speedup 1.0000x reference)
//
#include <hip/hip_runtime.h>
#include <stdint.h>

typedef unsigned short u16;
typedef __attribute__((ext_vector_type(8))) short short8;
typedef __attribute__((ext_vector_type(4))) float f32x4;

__device__ __forceinline__ u16 f2bf(float f) {
  uint32_t u = __builtin_bit_cast(uint32_t, f);
  u += 0x7fffu + ((u >> 16) & 1u);
  return (u16)(u >> 16);
}

__device__ __forceinline__ void gld16(const void* g, void* l) {
  __builtin_amdgcn_global_load_lds(
      (const __attribute__((address_space(1))) void*)g,
      (__attribute__((address_space(3))) void*)l, 16, 0, 0);
}

__device__ __forceinline__ void drain() {
  asm volatile("s_waitcnt vmcnt(0)" ::: "memory");
}

// ---------------------------------------------------------------------------
// Weight prep: MFMA-fragment-ordered bf16 weights (16x16 layout). Identical
// to the passing 381us version.
// wA: [cb 8][tap 9][kb 8][nl 192][kk 32], nl = q*96 + g*16 + cl:
//     c = cb*32 + q*16 + cl
//     g<3 : o = g*256 + c,     W = w_ih[:, :256] - w_ih[:,256:512]/5
//     g>=3: o = (g-3)*256 + c, W = w_hh
// wS: [cb 8][tap 9][kb 8][nl 96][kk 32], o = cb*96 + nl, W = w_ih[:,256:512]/5
// ---------------------------------------------------------------------------
__global__ __launch_bounds__(256) void k_wprep(const float* __restrict__ w_ih,
                                               const float* __restrict__ w_hh,
                                               u16* __restrict__ wA,
                                               u16* __restrict__ wS) {
  const int NA = 8*9*8*192*32;
  const int NS = 8*9*8*96*32;
  for (int idx = blockIdx.x*blockDim.x + threadIdx.x; idx < NA + NS;
       idx += gridDim.x*blockDim.x) {
    if (idx < NA) {
      int kk = idx & 31; int t = idx >> 5;
      int nl = t % 192; t /= 192;
      int kb = t & 7; t >>= 3;
      int tap = t % 9; int cb = t / 9;
      int qq = nl / 96; int rr = nl % 96;
      int g = rr >> 4, cl = rr & 15;
      int c = cb*32 + qq*16 + cl, ci = kb*32 + kk;
      float v;
      if (g < 3) {
        int o = g*256 + c;
        v = w_ih[(o*512 + ci)*9 + tap] - 0.2f * w_ih[(o*512 + 256 + ci)*9 + tap];
      } else {
        int o = (g-3)*256 + c;
        v = w_hh[(o*256 + ci)*9 + tap];
      }
      wA[idx] = f2bf(v);
    } else {
      int j = idx - NA;
      int kk = j & 31; int t = j >> 5;
      int nl = t % 96; t /= 96;
      int kb = t & 7; t >>= 3;
      int tap = t % 9; int cb = t / 9;
      int o = cb*96 + nl, ci = kb*32 + kk;
      wS[j] = f2bf(0.2f * w_ih[(o*512 + 256 + ci)*9 + tap]);
    }
  }
}

// ---------------------------------------------------------------------------
// NCHW fp32 master -> NHWC bf16 per-agent x, and per-batch agent-sum s.
// ---------------------------------------------------------------------------
__global__ __launch_bounds__(256) void k_xform(const float* __restrict__ src,
                                               u16* __restrict__ xbf,
                                               u16* __restrict__ sbf) {
  __shared__ float lds[32][33];
  const int t = threadIdx.x;
  const int tx = t & 31, ty = t >> 5;
  const int p0 = blockIdx.x*32, c0 = blockIdx.y*32, b = blockIdx.z;
  const int po = t >> 3, co = (t & 7)*4;
  float ss[4] = {0.f,0.f,0.f,0.f};
  for (int a = 0; a < 6; ++a) {
    const int im = b*6 + a;
    const float* sp = src + ((size_t)im*256 + c0)*1024 + p0;
    #pragma unroll
    for (int k = 0; k < 4; ++k) {
      float v = sp[(size_t)(ty + 8*k)*1024 + tx];
      ss[k] += v;
      lds[ty + 8*k][tx] = v;
    }
    __syncthreads();
    ushort4 pk = make_ushort4(f2bf(lds[co+0][po]), f2bf(lds[co+1][po]),
                              f2bf(lds[co+2][po]), f2bf(lds[co+3][po]));
    *(ushort4*)(xbf + ((size_t)im*1024 + p0+po)*256 + c0 + co) = pk;
    __syncthreads();
  }
  #pragma unroll
  for (int k = 0; k < 4; ++k) lds[ty + 8*k][tx] = ss[k];
  __syncthreads();
  ushort4 pk = make_ushort4(f2bf(lds[co+0][po]), f2bf(lds[co+1][po]),
                            f2bf(lds[co+2][po]), f2bf(lds[co+3][po]));
  *(ushort4*)(sbf + ((size_t)b*1024 + p0+po)*256 + c0 + co) = pk;
}

// ---------------------------------------------------------------------------
// Implicit-GEMM 3x3 conv, 16x16x32 MFMA.
// Block = 256 thr = 4 waves, each wave 1 image row x 96 N (6 gates in-lane).
// B-fragments read DIRECTLY global->reg (coalesced 1KB/wave-load, L2-resident
// per XCD), double-buffered one tap ahead; compiler auto-vmcnt before use.
// A slab (6 rows) in LDS via global_load_lds, double-buffered per kb; the
// ONLY barrier is at kb boundaries (waves drift within a kb).
// GATES: (cb,q) n-slice from bid&15, fused GRU epilogue; else s-conv.
// ---------------------------------------------------------------------------
template<bool GATES>
__global__ __launch_bounds__(256, 3)
void k_conv(const u16* __restrict__ xin, const u16* __restrict__ wpre,
            float* __restrict__ gsbuf,
            const float* __restrict__ b_ih, const float* __restrict__ b_hh,
            const float* __restrict__ h_in, float* __restrict__ h_out) {
  constexpr int BNROW = GATES ? 192 : 96;
  constexpr int BN    = BNROW * 32;      // elements per (cb,tap,kb) B slice
  constexpr int SLAB  = 6*32*32;         // u16 per A buffer (6 rows)
  constexpr int TOTA  = 6*128;           // 16B loads per A stage (3/thread)
  __shared__ __align__(16) u16 slab[2][SLAB];

  const int tid = threadIdx.x;
  const int l   = tid & 63;
  const int rg  = tid >> 6;              // wave = row within block (0..3)
  const int lx  = l & 15;
  const int lk  = l >> 4;

  int cb, q, rest;
  if constexpr (GATES) {
    const int nsl = blockIdx.x & 15;
    cb = nsl & 7; q = nsl >> 3; rest = blockIdx.x >> 4;
  } else {
    cb = blockIdx.x & 7; q = 0; rest = blockIdx.x >> 3;
  }
  const int mt  = rest & 7;
  const int img = rest >> 3;
  const int h0  = mt * 4;

  const u16* srcimg = xin + (size_t)img * (1024*256);
  // per-lane B fragment pointer (element offset): nl = q*96 + g*16 + lx, k-chunk lk
  const u16* wlane = wpre + (q*96 + lx)*32 + lk*8;

  auto stageA = [&](int kb, int sbuf) {
    #pragma unroll
    for (int ii = 0; ii < 3; ++ii) {
      int i = ii*256 + tid;
      int p = i >> 2, ck = i & 3;
      int pr = p >> 5, pc = p & 31;
      int gr = h0 - 1 + pr;
      gr = gr < 0 ? 0 : (gr > 31 ? 31 : gr);
      int sck = ck ^ ((p >> 1) & 3);
      gld16(srcimg + (gr*32 + pc)*256 + kb*32 + sck*8, &slab[sbuf][i*8]);
    }
  };

  auto loadA = [&](short8 (&a)[2], int DY, int DX, int ssel) {
    const int grow = h0 + rg + DY - 1;
    const bool rowok = (grow >= 0) && (grow < 32);
    const int sr = rg + DY;
    #pragma unroll
    for (int mi = 0; mi < 2; ++mi) {
      const int cc = mi*16 + lx + DX - 1;
      const bool ok = rowok && (cc >= 0) && (cc < 32);
      const int ccc = cc < 0 ? 0 : (cc > 31 ? 31 : cc);
      short8 av = *(const short8*)&slab[ssel][(sr*32 + ccc)*32 + (lk ^ ((ccc >> 1) & 3))*8];
      if (!ok) av = (short8){0,0,0,0,0,0,0,0};
      a[mi] = av;
    }
  };

  f32x4 acc[2][6];
  #pragma unroll
  for (int mi = 0; mi < 2; ++mi)
    #pragma unroll
    for (int g = 0; g < 6; ++g) acc[mi][g] = (f32x4){0.f,0.f,0.f,0.f};

  short8 b[2][6];

  // prologue: A slab for kb0, drain; B for (kb0,tap0) into b[0]; sync
  stageA(0, 0);
  drain();
  {
    const u16* wb = wlane + (size_t)((cb*9 + 0)*8 + 0) * BN;
    #pragma unroll
    for (int g = 0; g < 6; ++g) b[0][g] = *(const short8*)(wb + g*512);
  }
  __builtin_amdgcn_s_barrier();
  __builtin_amdgcn_sched_barrier(0);

  for (int kbp = 0; kbp < 4; ++kbp) {
    #pragma unroll
    for (int kb2 = 0; kb2 < 2; ++kb2) {
      const int kb = kbp*2 + kb2;
      const int sb = kb2;                      // kb & 1
      #pragma unroll
      for (int tap = 0; tap < 9; ++tap) {
        const int cur = (kb2 + tap) & 1;       // compile-time under unroll
        const int nxt = cur ^ 1;

        // 1. issue next tap's B loads (deepest latency first)
        if (!(kb == 7 && tap == 8)) {
          const int nkb  = (tap < 8) ? kb : kb + 1;
          const int ntap = (tap < 8) ? tap + 1 : 0;
          const u16* wb = wlane + (size_t)((cb*9 + ntap)*8 + nkb) * BN;
          #pragma unroll
          for (int g = 0; g < 6; ++g) b[nxt][g] = *(const short8*)(wb + g*512);
        }
        // 2. A slab prefetch for next kb
        if (tap == 6 && kb < 7) stageA(kb+1, sb^1);
        // 3. A fragments for this tap
        short8 a[2];
        loadA(a, tap/3, tap%3, sb);
        // 4. MFMA (compiler inserts precise vmcnt/lgkmcnt before first use)
        __builtin_amdgcn_s_setprio(1);
        #pragma unroll
        for (int g = 0; g < 6; ++g) {
          acc[0][g] = __builtin_amdgcn_mfma_f32_16x16x32_bf16(a[0], b[cur][g], acc[0][g], 0, 0, 0);
          acc[1][g] = __builtin_amdgcn_mfma_f32_16x16x32_bf16(a[1], b[cur][g], acc[1][g], 0, 0, 0);
        }
        __builtin_amdgcn_s_setprio(0);
        // 5. kb boundary: drain A-slab loads, block-wide sync
        if (tap == 8) {
          drain();
          __builtin_amdgcn_sched_barrier(0);
          __builtin_amdgcn_s_barrier();
          __builtin_amdgcn_sched_barrier(0);
        }
      }
    }
  }

  if constexpr (GATES) {
    const int bat = img / 6;
    const int c = cb*32 + q*16 + lx;
    const float bir = b_ih[c],  bii = b_ih[256+c], bin_ = b_ih[512+c];
    const float bhr = b_hh[c],  bhi = b_hh[256+c], bhn  = b_hh[512+c];
    const float* gs0 = gsbuf + ((size_t)(bat*3+0)*256 + c)*1024;
    const float* gs1 = gsbuf + ((size_t)(bat*3+1)*256 + c)*1024;
    const float* gs2 = gsbuf + ((size_t)(bat*3+2)*256 + c)*1024;
    const float* hp  = h_in  + ((size_t)img*256 + c)*1024;
    float*       op  = h_out + ((size_t)img*256 + c)*1024;
    const int R = h0 + rg;
    #pragma unroll
    for (int mi = 0; mi < 2; ++mi) {
      const int pix = R*32 + mi*16 + lk*4;
      float4 v0 = *(const float4*)(gs0 + pix);
      float4 v1 = *(const float4*)(gs1 + pix);
      float4 v2 = *(const float4*)(gs2 + pix);
      float4 hv = *(const float4*)(hp + pix);
      float4 o;
      #pragma unroll
      for (int r = 0; r < 4; ++r) {
        float ir  = acc[mi][0][r] + (&v0.x)[r] + bir;
        float ii  = acc[mi][1][r] + (&v1.x)[r] + bii;
        float inn = acc[mi][2][r] + (&v2.x)[r] + bin_;
        float hr  = acc[mi][3][r] + bhr;
        float hi2 = acc[mi][4][r] + bhi;
        float hn  = acc[mi][5][r] + bhn;
        float rgt = 1.f/(1.f + __expf(-(ir+hr)));
        float igt = 1.f/(1.f + __expf(-(ii+hi2)));
        float nx = inn + rgt*hn;
        nx = nx > 20.f ? 20.f : (nx < -20.f ? -20.f : nx);
        float e2 = __expf(-2.f*nx);
        float ng = (1.f - e2)/(1.f + e2);
        (&o.x)[r] = ng + igt*((&hv.x)[r] - ng);
      }
      *(float4*)(op + pix) = o;
    }
  } else {
    const int R = h0 + rg;
    #pragma unroll
    for (int g = 0; g < 6; ++g) {
      const int n = cb*96 + g*16 + lx;
      float* gp = gsbuf + ((size_t)img*768 + n)*1024;
      #pragma unroll
      for (int mi = 0; mi < 2; ++mi) {
        const int pix = R*32 + mi*16 + lk*4;
        *(float4*)(gp + pix) = make_float4(acc[mi][g][0], acc[mi][g][1],
                                           acc[mi][g][2], acc[mi][g][3]);
      }
    }
  }
}

// ---------------------------------------------------------------------------
extern "C" void kernel_launch(void* const* d_in, const int* in_sizes, int n_in,
                              void* d_out, int out_size, void* d_ws, size_t ws_size,
                              hipStream_t stream) {
  const float* x    = (const float*)d_in[0];
  const float* w_ih = (const float*)d_in[1];
  const float* w_hh = (const float*)d_in[2];
  const float* b_ih = (const float*)d_in[3];
  const float* b_hh = (const float*)d_in[4];
  float* out = (float*)d_out;

  char* ws = (char*)d_ws;
  float* m0  = (float*)(ws);                 // master scratch (iter-1 output)
  u16*  xbf  = (u16*)(ws + 50331648);        // x bf16 NHWC
  u16*  sbf  = (u16*)(ws + 75497472);        // s bf16 NHWC
  float* gsb = (float*)(ws + 79691776);      // gs fp32
  u16*  wA   = (u16*)(ws + 104857600);
  u16*  wS   = (u16*)(ws + 111935488);

  k_wprep<<<2048, 256, 0, stream>>>(w_ih, w_hh, wA, wS);

  for (int it = 0; it < 3; ++it) {
    const float* src = (it == 0) ? x : (it == 1 ? out : m0);
    float* dst = (it == 1) ? m0 : out;
    k_xform<<<dim3(32, 8, 8), 256, 0, stream>>>(src, xbf, sbf);
    // s-conv: 8 cb x 8 mt x 8 batches
    k_conv<false><<<512, 256, 0, stream>>>(sbf, wS, gsb,
                                           nullptr, nullptr, nullptr, nullptr);
    // main conv: 16 (cb,q) x 8 mt x 48 imgs
    k_conv<true><<<6144, 256, 0, stream>>>(xbf, wA, gsb,
                                           b_ih, b_hh, src, dst);
  }
}